// Round 1
// baseline (670.972 us; speedup 1.0000x reference)
//
#include <hip/hip_runtime.h>
#include <hip/hip_bf16.h>

typedef __attribute__((ext_vector_type(4))) float f32x4;
typedef __attribute__((ext_vector_type(4))) float float4_t;
typedef __attribute__((ext_vector_type(8))) __bf16 bf16x8;
typedef __attribute__((ext_vector_type(4))) __bf16 bf16x4;

#define DEVI static __device__ __forceinline__

DEVI int swz_off(int row, int b) { return row * 128 + (b ^ ((row & 7) << 4)); }

// ---------------------------------------------------------------------------
// Generic tiled GEMM: C[M,N] = A[M,K] * B[K,N].
//  - A: f32 (ADT=0, converted to bf16 while staging) or bf16 (ADT=1)
//  - B: given TRANSPOSED as BT[N,K] bf16 (k-contiguous)
//  - SWAP=1: mfma operands swapped -> acc = C^T tile, transposed epilogues
//  - EPI: 0 = f32 C[m*ldc+n] (non-swap)
//         1 = bf16 CT[n*8000+m]
//         2 = G2 special: relu->ET, n<64: ZbT + f32 hidden (scattered)
//         3 = f32 CT[n*8000+m]
// All M are 8000 here; K divisible by 64; BK=64 fixed.
// LDS rows are 64 bf16 = 128B, XOR-swizzled by ((row&7)<<4) on byte offset.
// ---------------------------------------------------------------------------
template<int BM, int BN, int WM, int WN, int ADT, int SWAP, int EPI>
__global__ __launch_bounds__(WM * WN * 64)
void gemm_tpl(const void* __restrict__ Ap, const __bf16* __restrict__ BT,
              void* __restrict__ o0, void* __restrict__ o1, void* __restrict__ o2,
              int K, int lda, int ldbt, int ldc, int nbn) {
  constexpr int T = WM * WN * 64;
  constexpr int TM = BM / WM, TN = BN / WN;
  constexpr int FM = TM / 16, FN = TN / 16;
  static_assert(TM % 16 == 0 && TN % 16 == 0, "wave tile must be 16-divisible");
  __shared__ __align__(16) char lds[(BM + BN) * 128];
  const int tid = threadIdx.x;
  const int bid = blockIdx.x;
  const int m0 = (bid / nbn) * BM, n0 = (bid % nbn) * BN;
  const int lane = tid & 63, wid = tid >> 6;
  const int wm = wid / WN, wn = wid % WN;
  const int r16 = lane & 15, hi = lane >> 4;

  f32x4 acc[FM][FN];
#pragma unroll
  for (int a = 0; a < FM; ++a)
#pragma unroll
    for (int b = 0; b < FN; ++b) acc[a][b] = (f32x4){0.f, 0.f, 0.f, 0.f};

  const int nk = K >> 6;
  for (int kt = 0; kt < nk; ++kt) {
    const int k0 = kt << 6;
    // ---- stage A tile [BM][64] into LDS (bf16, swizzled) ----
    if constexpr (ADT == 0) {
      const float* Af = (const float*)Ap;
      for (int c = tid; c < BM * 16; c += T) {
        const int r = c >> 4, c4 = c & 15;
        float4_t v = *(const float4_t*)(Af + (size_t)(m0 + r) * lda + k0 + c4 * 4);
        bf16x4 bv;
        bv.x = (__bf16)v.x; bv.y = (__bf16)v.y; bv.z = (__bf16)v.z; bv.w = (__bf16)v.w;
        *(bf16x4*)(lds + swz_off(r, c4 * 8)) = bv;
      }
    } else {
      const __bf16* Ab = (const __bf16*)Ap;
      for (int c = tid; c < BM * 8; c += T) {
        const int r = c >> 3, k8 = c & 7;
        bf16x8 v = *(const bf16x8*)(Ab + (size_t)(m0 + r) * lda + k0 + k8 * 8);
        *(bf16x8*)(lds + swz_off(r, k8 * 16)) = v;
      }
    }
    // ---- stage B tile [BN][64] from BT (already k-contiguous) ----
    for (int c = tid; c < BN * 8; c += T) {
      const int n = c >> 3, k8 = c & 7;
      bf16x8 v = *(const bf16x8*)(BT + (size_t)(n0 + n) * ldbt + k0 + k8 * 8);
      *(bf16x8*)(lds + swz_off(BM + n, k8 * 16)) = v;
    }
    __syncthreads();
#pragma unroll
    for (int kk = 0; kk < 2; ++kk) {
      bf16x8 af[FM], bfv[FN];
#pragma unroll
      for (int f = 0; f < FM; ++f)
        af[f] = *(const bf16x8*)(lds + swz_off(wm * TM + f * 16 + r16, kk * 64 + hi * 16));
#pragma unroll
      for (int f = 0; f < FN; ++f)
        bfv[f] = *(const bf16x8*)(lds + swz_off(BM + wn * TN + f * 16 + r16, kk * 64 + hi * 16));
#pragma unroll
      for (int a = 0; a < FM; ++a)
#pragma unroll
        for (int b = 0; b < FN; ++b) {
          if constexpr (SWAP)
            acc[a][b] = __builtin_amdgcn_mfma_f32_16x16x32_bf16(bfv[b], af[a], acc[a][b], 0, 0, 0);
          else
            acc[a][b] = __builtin_amdgcn_mfma_f32_16x16x32_bf16(af[a], bfv[b], acc[a][b], 0, 0, 0);
        }
    }
    __syncthreads();
  }
  // ---- epilogue ----
#pragma unroll
  for (int a = 0; a < FM; ++a) {
#pragma unroll
    for (int b = 0; b < FN; ++b) {
#pragma unroll
      for (int r = 0; r < 4; ++r) {
        const float v = acc[a][b][r];
        if constexpr (!SWAP) {
          const int m = m0 + wm * TM + a * 16 + hi * 4 + r;
          const int n = n0 + wn * TN + b * 16 + r16;
          if constexpr (EPI == 0) ((float*)o0)[(size_t)m * ldc + n] = v;
        } else {
          const int n = n0 + wn * TN + b * 16 + hi * 4 + r;
          const int m = m0 + wm * TM + a * 16 + r16;
          if constexpr (EPI == 1) {
            ((__bf16*)o0)[(size_t)n * 8000 + m] = (__bf16)v;
          } else if constexpr (EPI == 2) {
            ((__bf16*)o0)[(size_t)n * 8000 + m] = (__bf16)fmaxf(v, 0.f); // ET (relu)
            if (n < 64) {
              ((__bf16*)o1)[(size_t)n * 8000 + m] = (__bf16)v;           // ZbT
              ((float*)o2)[(size_t)m * 64 + n] = v;                      // hidden_emb
            }
          } else if constexpr (EPI == 3) {
            ((float*)o0)[(size_t)n * 8000 + m] = v;
          }
        }
      }
    }
  }
}

// ---------------------------------------------------------------------------
// prep: transpose+convert weights to bf16, build block-diag disc matrix,
// fill ones/zeros rows of ET (rows 128..143), write clustering_loss=0.
// ---------------------------------------------------------------------------
__global__ void prep_kernel(const float* __restrict__ w1, const float* __restrict__ w2,
                            const float* __restrict__ dw,
                            __bf16* __restrict__ W1bT, __bf16* __restrict__ W2bT,
                            __bf16* __restrict__ WdT, __bf16* __restrict__ ET,
                            float* __restrict__ loss_out) {
  const int total = 65536 + 65536 + 16384 + 16 * 8000;
  for (int i = blockIdx.x * blockDim.x + threadIdx.x; i < total; i += gridDim.x * blockDim.x) {
    if (i < 65536) {                       // W1bT[n][k] = w1[k][n], [64][1024]
      const int n = i >> 10, k = i & 1023;
      W1bT[i] = (__bf16)w1[k * 64 + n];
    } else if (i < 131072) {               // W2bT[n][k] = w2[k][n], [1024][64]
      const int j = i - 65536;
      const int n = j >> 6, k = j & 63;
      W2bT[j] = (__bf16)w2[k * 1024 + n];
    } else if (i < 147456) {               // WdT[n][k] block-diag(disc_w^T), [128][128]
      const int j = i - 131072;
      const int n = j >> 7, k = j & 127;
      float v = 0.f;
      if (n < 64 && k < 64) v = dw[k * 64 + n];
      else if (n >= 64 && k >= 64) v = dw[(k - 64) * 64 + (n - 64)];
      WdT[j] = (__bf16)v;
    } else {                               // ET rows 128..143: row128=1, rest 0
      const int j = i - 147456;
      const int rr = j / 8000, m = j - rr * 8000;
      ET[(size_t)(128 + rr) * 8000 + m] = (__bf16)(rr == 0 ? 1.f : 0.f);
    }
  }
  if (blockIdx.x == 0 && threadIdx.x == 0) *loss_out = 0.f;
}

// ---------------------------------------------------------------------------
// transpose ET rows 0..127 -> E[8000][128] (bf16), LDS-tiled
// ---------------------------------------------------------------------------
__global__ __launch_bounds__(256) void transpose_kernel(const __bf16* __restrict__ ET,
                                                        __bf16* __restrict__ E) {
  __shared__ __bf16 Lt[128][72];
  const int m0 = blockIdx.x * 64;
  const int tid = threadIdx.x;
  for (int c = tid; c < 128 * 8; c += 256) {
    const int n = c >> 3, m8 = c & 7;
    bf16x8 v = *(const bf16x8*)(ET + (size_t)n * 8000 + m0 + m8 * 8);
    *(bf16x8*)(&Lt[n][m8 * 8]) = v;
  }
  __syncthreads();
  for (int c = tid; c < 64 * 16; c += 256) {
    const int m = c >> 4, n8 = c & 15;
    bf16x8 v;
#pragma unroll
    for (int j = 0; j < 8; ++j) v[j] = Lt[n8 * 8 + j][m];
    *(bf16x8*)(E + (size_t)(m0 + m) * 128 + n8 * 8) = v;
  }
}

// ---------------------------------------------------------------------------
// final: per row m: rs = GNT[128][m]; per half: l2-normalize(GNT/rs), sigmoid,
// dot against P/Q columns from PQT; write ret / ret_a.
// ---------------------------------------------------------------------------
__global__ __launch_bounds__(256) void final_kernel(const float* __restrict__ GNT,
                                                    const float* __restrict__ PQT,
                                                    const float* __restrict__ bptr,
                                                    float* __restrict__ out_ret,
                                                    float* __restrict__ out_reta) {
  const int m = blockIdx.x * 256 + threadIdx.x;
  if (m >= 8000) return;
  const float b = bptr[0];
  const float inv_rs = 1.f / GNT[(size_t)128 * 8000 + m];
  float r1 = 0, r2 = 0, ra1 = 0, ra2 = 0;
#pragma unroll
  for (int h = 0; h < 2; ++h) {
    float ss = 0.f;
    for (int n = 0; n < 64; ++n) {
      const float t = GNT[(size_t)(h * 64 + n) * 8000 + m] * inv_rs;
      ss += t * t;
    }
    float nrm = fmaxf(sqrtf(ss), 1e-12f);
    const float inv = inv_rs / nrm;
    float s_p = 0.f, s_q = 0.f;
    for (int n = 0; n < 64; ++n) {
      const float t = GNT[(size_t)(h * 64 + n) * 8000 + m] * inv;
      const float g = 1.f / (1.f + expf(-t));
      s_p += PQT[(size_t)n * 8000 + m] * g;
      s_q += PQT[(size_t)(64 + n) * 8000 + m] * g;
    }
    if (h == 0) { r1 = s_p + b; r2 = s_q + b; }
    else        { ra1 = s_q + b; ra2 = s_p + b; }
  }
  out_ret[m * 2] = r1;  out_ret[m * 2 + 1] = r2;
  out_reta[m * 2] = ra1; out_reta[m * 2 + 1] = ra2;
}

// ---------------------------------------------------------------------------
extern "C" void kernel_launch(void* const* d_in, const int* in_sizes, int n_in,
                              void* d_out, int out_size, void* d_ws, size_t ws_size,
                              hipStream_t stream) {
  const float* feat   = (const float*)d_in[0];
  const float* feat_a = (const float*)d_in[1];
  const float* adj    = (const float*)d_in[2];
  const float* gneigh = (const float*)d_in[3];
  const float* w1     = (const float*)d_in[4];
  const float* w2     = (const float*)d_in[5];
  const float* dw     = (const float*)d_in[6];
  const float* db     = (const float*)d_in[7];

  float* out      = (float*)d_out;
  float* out_hid  = out;                 // [8000,64]
  float* out_h    = out + 512000;        // [8000,1024]
  float* out_ret  = out + 8704000;       // [8000,2]
  float* out_reta = out + 8720000;       // [8000,2]
  float* out_loss = out + 8736000;       // scalar

  char* ws = (char*)d_ws;
  __bf16* R1T  = (__bf16*)(ws);              // [128][8000] = [fw1|fa1]^T
  __bf16* ET   = (__bf16*)(ws + 2048000);    // [144][8000] = [emb|emb_a|1|0]^T
  __bf16* ZbT  = (__bf16*)(ws + 4352000);    // [64][8000]  = z^T
  __bf16* E    = (__bf16*)(ws + 5376000);    // [8000][128] = [emb|emb_a]
  float*  Yf   = (float*) (ws + 7424000);    // [8000][64]  = adj@z
  float*  GNT  = (float*) (ws + 9472000);    // [144][8000]
  float*  PQT  = (float*) (ws + 14080000);   // [128][8000]
  __bf16* WdT  = (__bf16*)(ws + 18176000);   // [128][128]
  __bf16* W1bT = (__bf16*)(ws + 18208768);   // [64][1024]
  __bf16* W2bT = (__bf16*)(ws + 18339840);   // [1024][64]

  prep_kernel<<<512, 256, 0, stream>>>(w1, w2, dw, W1bT, W2bT, WdT, ET, out_loss);

  // R1T = (feat@W1)^T and (feat_a@W1)^T    M=8000 K=1024 N=64 each
  gemm_tpl<32, 64, 1, 4, 0, 1, 1><<<250, 256, 0, stream>>>(
      feat, W1bT, R1T, nullptr, nullptr, 1024, 1024, 1024, 0, 1);
  gemm_tpl<32, 64, 1, 4, 0, 1, 1><<<250, 256, 0, stream>>>(
      feat_a, W1bT, R1T + (size_t)64 * 8000, nullptr, nullptr, 1024, 1024, 1024, 0, 1);

  // S^T = (adj @ [fw1|fa1])^T : ET(relu), ZbT, hidden_emb   M=8000 K=8000 N=128
  gemm_tpl<32, 128, 2, 4, 0, 1, 2><<<250, 512, 0, stream>>>(
      adj, R1T, ET, ZbT, out_hid, 8000, 8000, 8000, 0, 1);

  transpose_kernel<<<125, 256, 0, stream>>>(ET, E);

  // Y = adj @ z                         M=8000 K=8000 N=64
  gemm_tpl<32, 64, 2, 4, 0, 0, 0><<<250, 512, 0, stream>>>(
      adj, ZbT, Yf, nullptr, nullptr, 8000, 8000, 8000, 64, 1);

  // h = Y @ W2                          M=8000 K=64 N=1024
  gemm_tpl<64, 128, 2, 2, 0, 0, 0><<<1000, 256, 0, stream>>>(
      Yf, W2bT, out_h, nullptr, nullptr, 64, 64, 64, 1024, 8);

  // GNT = (graph_neigh @ [emb|emb_a|1])^T   M=8000 K=8000 N=144
  gemm_tpl<32, 144, 2, 3, 0, 1, 3><<<250, 384, 0, stream>>>(
      gneigh, ET, GNT, nullptr, nullptr, 8000, 8000, 8000, 0, 1);

  // PQT = (E @ blockdiag(disc_w))^T     M=8000 K=128 N=128
  gemm_tpl<32, 128, 1, 4, 1, 1, 3><<<250, 256, 0, stream>>>(
      E, WdT, PQT, nullptr, nullptr, 128, 128, 128, 0, 1);

  final_kernel<<<32, 256, 0, stream>>>(GNT, PQT, db, out_ret, out_reta);
}

// Round 2
// 349.941 us; speedup vs baseline: 1.9174x; 1.9174x over previous
//
#include <hip/hip_runtime.h>
#include <hip/hip_bf16.h>

typedef __attribute__((ext_vector_type(4))) float f32x4;
typedef __attribute__((ext_vector_type(8))) __bf16 bf16x8;
typedef __attribute__((ext_vector_type(4))) __bf16 bf16x4;

static __device__ __forceinline__ int swz_off(int row, int b) {
  return row * 128 + (b ^ ((row & 7) << 4));
}

static __device__ __forceinline__ void atomic_add_f32(float* p, float v) {
  asm volatile("global_atomic_add_f32 %0, %1, off" :: "v"(p), "v"(v) : "memory");
}

// ---------------------------------------------------------------------------
// Split-K tiled GEMM: C[M,N] = A[M,K] * B[K,N]
//  - A: f32 (ADT=0, converted to bf16 while staging) or bf16 (ADT=1)
//  - B: TRANSPOSED BT[N,K] bf16, k-contiguous
//  - grid = nks * nmb * nbn  (bijective XCD swizzle applied to blockIdx)
//  - EPI: 0 = f32 store C[m*ldc+n]            (non-swap)
//         5 = f32 atomicAdd C[m*ldc+n]        (non-swap, split-K)
//         1 = bf16 store CT[(n+noff)*8000+m]  (swap; noff=BN for 2nd A matrix)
//         3 = f32 store CT[n*8000+m]          (swap)
//         4 = f32 atomicAdd CT[n*8000+m]      (swap, split-K)
// LDS rows 64 bf16 = 128B, XOR-swizzled ((row&7)<<4) on byte offset.
// ---------------------------------------------------------------------------
template<int BM, int BN, int WM, int WN, int ADT, int SWAP, int EPI>
__global__ __launch_bounds__(WM * WN * 64)
void gemm_tpl(const void* __restrict__ Ap, const void* __restrict__ A2p,
              const __bf16* __restrict__ BT, void* __restrict__ o0,
              int lda, int ldbt, int ldc, int nmb, int nbn, int ktps, int mA) {
  constexpr int T = WM * WN * 64;
  constexpr int TM = BM / WM, TN = BN / WN;
  constexpr int FM = TM / 16, FN = TN / 16;
  static_assert(TM % 16 == 0 && TN % 16 == 0, "wave tile must be 16-divisible");
  __shared__ __align__(16) char lds[(BM + BN) * 128];
  const int tid = threadIdx.x;

  // bijective XCD-chunk swizzle (8 XCDs)
  const int nwg = gridDim.x;
  const int q = nwg >> 3, r8 = nwg & 7;
  const int xcd = blockIdx.x & 7, sidx = blockIdx.x >> 3;
  const int wgid = (xcd < r8 ? xcd * (q + 1) : r8 * (q + 1) + (xcd - r8) * q) + sidx;
  const int ks = wgid / (nmb * nbn);
  const int rem = wgid % (nmb * nbn);
  const int mb = rem / nbn, nb = rem % nbn;

  int m0 = mb * BM;
  const int n0 = nb * BN;
  const void* Asel = Ap;
  int noff = 0;
  if (m0 >= mA) { Asel = A2p; m0 -= mA; noff = BN; }

  const int lane = tid & 63, wid = tid >> 6;
  const int wm = wid / WN, wn = wid % WN;
  const int r16 = lane & 15, hi = lane >> 4;

  f32x4 acc[FM][FN];
#pragma unroll
  for (int a = 0; a < FM; ++a)
#pragma unroll
    for (int b = 0; b < FN; ++b) acc[a][b] = (f32x4){0.f, 0.f, 0.f, 0.f};

  const int kt0 = ks * ktps;
  for (int kt = kt0; kt < kt0 + ktps; ++kt) {
    const int k0 = kt << 6;
    if constexpr (ADT == 0) {
      const float* Af = (const float*)Asel;
      for (int c = tid; c < BM * 16; c += T) {
        const int r = c >> 4, c4 = c & 15;
        f32x4 v = *(const f32x4*)(Af + (size_t)(m0 + r) * lda + k0 + c4 * 4);
        bf16x4 bv;
        bv.x = (__bf16)v.x; bv.y = (__bf16)v.y; bv.z = (__bf16)v.z; bv.w = (__bf16)v.w;
        *(bf16x4*)(lds + swz_off(r, c4 * 8)) = bv;
      }
    } else {
      const __bf16* Ab = (const __bf16*)Asel;
      for (int c = tid; c < BM * 8; c += T) {
        const int r = c >> 3, k8 = c & 7;
        bf16x8 v = *(const bf16x8*)(Ab + (size_t)(m0 + r) * lda + k0 + k8 * 8);
        *(bf16x8*)(lds + swz_off(r, k8 * 16)) = v;
      }
    }
    for (int c = tid; c < BN * 8; c += T) {
      const int n = c >> 3, k8 = c & 7;
      bf16x8 v = *(const bf16x8*)(BT + (size_t)(n0 + n) * ldbt + k0 + k8 * 8);
      *(bf16x8*)(lds + swz_off(BM + n, k8 * 16)) = v;
    }
    __syncthreads();
#pragma unroll
    for (int kk = 0; kk < 2; ++kk) {
      bf16x8 af[FM], bfv[FN];
#pragma unroll
      for (int f = 0; f < FM; ++f)
        af[f] = *(const bf16x8*)(lds + swz_off(wm * TM + f * 16 + r16, kk * 64 + hi * 16));
#pragma unroll
      for (int f = 0; f < FN; ++f)
        bfv[f] = *(const bf16x8*)(lds + swz_off(BM + wn * TN + f * 16 + r16, kk * 64 + hi * 16));
#pragma unroll
      for (int a = 0; a < FM; ++a)
#pragma unroll
        for (int b = 0; b < FN; ++b) {
          if constexpr (SWAP)
            acc[a][b] = __builtin_amdgcn_mfma_f32_16x16x32_bf16(bfv[b], af[a], acc[a][b], 0, 0, 0);
          else
            acc[a][b] = __builtin_amdgcn_mfma_f32_16x16x32_bf16(af[a], bfv[b], acc[a][b], 0, 0, 0);
        }
    }
    __syncthreads();
  }
  // ---- epilogue ----
#pragma unroll
  for (int a = 0; a < FM; ++a) {
#pragma unroll
    for (int b = 0; b < FN; ++b) {
#pragma unroll
      for (int r = 0; r < 4; ++r) {
        const float v = acc[a][b][r];
        if constexpr (!SWAP) {
          const int m = m0 + wm * TM + a * 16 + hi * 4 + r;
          const int n = n0 + wn * TN + b * 16 + r16;
          if constexpr (EPI == 0) ((float*)o0)[(size_t)m * ldc + n] = v;
          else if constexpr (EPI == 5) atomic_add_f32(&((float*)o0)[(size_t)m * ldc + n], v);
        } else {
          const int n = n0 + wn * TN + b * 16 + hi * 4 + r;
          const int m = m0 + wm * TM + a * 16 + r16;
          if constexpr (EPI == 1) ((__bf16*)o0)[(size_t)(n + noff) * 8000 + m] = (__bf16)v;
          else if constexpr (EPI == 3) ((float*)o0)[(size_t)n * 8000 + m] = v;
          else if constexpr (EPI == 4) atomic_add_f32(&((float*)o0)[(size_t)n * 8000 + m], v);
        }
      }
    }
  }
}

// ---------------------------------------------------------------------------
// prep: weights -> bf16 transposed, block-diag disc matrix, ET pad rows, loss
// ---------------------------------------------------------------------------
__global__ void prep_kernel(const float* __restrict__ w1, const float* __restrict__ w2,
                            const float* __restrict__ dw,
                            __bf16* __restrict__ W1bT, __bf16* __restrict__ W2bT,
                            __bf16* __restrict__ WdT, __bf16* __restrict__ ET,
                            float* __restrict__ loss_out) {
  const int total = 65536 + 65536 + 16384 + 16 * 8000;
  for (int i = blockIdx.x * blockDim.x + threadIdx.x; i < total; i += gridDim.x * blockDim.x) {
    if (i < 65536) {                       // W1bT[n][k] = w1[k][n], [64][1024]
      const int n = i >> 10, k = i & 1023;
      W1bT[i] = (__bf16)w1[k * 64 + n];
    } else if (i < 131072) {               // W2bT[n][k] = w2[k][n], [1024][64]
      const int j = i - 65536;
      const int n = j >> 6, k = j & 63;
      W2bT[j] = (__bf16)w2[k * 1024 + n];
    } else if (i < 147456) {               // WdT block-diag(disc_w^T), [128][128]
      const int j = i - 131072;
      const int n = j >> 7, k = j & 127;
      float v = 0.f;
      if (n < 64 && k < 64) v = dw[k * 64 + n];
      else if (n >= 64 && k >= 64) v = dw[(k - 64) * 64 + (n - 64)];
      WdT[j] = (__bf16)v;
    } else {                               // ET rows 128..143: row128=1, rest 0
      const int j = i - 147456;
      const int rr = j / 8000, m = j - rr * 8000;
      ET[(size_t)(128 + rr) * 8000 + m] = (__bf16)(rr == 0 ? 1.f : 0.f);
    }
  }
  if (blockIdx.x == 0 && threadIdx.x == 0) *loss_out = 0.f;
}

// ---------------------------------------------------------------------------
// fixup_S: SfT f32 [128][8000] -> ET bf16 (relu, rows0..127), ZbT bf16 (rows
// 0..63, no relu), E bf16 [8000][128] (relu), hid f32 [8000][64] (no relu)
// ---------------------------------------------------------------------------
__global__ __launch_bounds__(256)
void fixup_S(const float* __restrict__ SfT, __bf16* __restrict__ ET,
             __bf16* __restrict__ ZbT, __bf16* __restrict__ E,
             float* __restrict__ hid) {
  __shared__ float Lt[128][36];
  const int m0 = blockIdx.x * 32;
  const int tid = threadIdx.x;
  for (int c = tid; c < 128 * 8; c += 256) {
    const int n = c >> 3, j4 = c & 7;
    f32x4 v = *(const f32x4*)(SfT + (size_t)n * 8000 + m0 + j4 * 4);
    *(f32x4*)(&Lt[n][j4 * 4]) = v;
    bf16x4 rb;
    rb.x = (__bf16)fmaxf(v.x, 0.f); rb.y = (__bf16)fmaxf(v.y, 0.f);
    rb.z = (__bf16)fmaxf(v.z, 0.f); rb.w = (__bf16)fmaxf(v.w, 0.f);
    *(bf16x4*)(ET + (size_t)n * 8000 + m0 + j4 * 4) = rb;
    if (n < 64) {
      bf16x4 zb;
      zb.x = (__bf16)v.x; zb.y = (__bf16)v.y; zb.z = (__bf16)v.z; zb.w = (__bf16)v.w;
      *(bf16x4*)(ZbT + (size_t)n * 8000 + m0 + j4 * 4) = zb;
    }
  }
  __syncthreads();
  for (int c = tid; c < 32 * 16; c += 256) {   // hid[m][n], n 0..63 (f32x4)
    const int mm = c >> 4, n4 = c & 15;
    f32x4 v;
    v.x = Lt[n4 * 4 + 0][mm]; v.y = Lt[n4 * 4 + 1][mm];
    v.z = Lt[n4 * 4 + 2][mm]; v.w = Lt[n4 * 4 + 3][mm];
    *(f32x4*)(hid + (size_t)(m0 + mm) * 64 + n4 * 4) = v;
  }
  for (int c = tid; c < 32 * 16; c += 256) {   // E[m][n], n 0..127 (bf16x8, relu)
    const int mm = c >> 4, n8 = c & 15;
    bf16x8 v;
#pragma unroll
    for (int j = 0; j < 8; ++j) v[j] = (__bf16)fmaxf(Lt[n8 * 8 + j][mm], 0.f);
    *(bf16x8*)(E + (size_t)(m0 + mm) * 128 + n8 * 8) = v;
  }
}

// ---------------------------------------------------------------------------
// final: per row m: rs = GNT[128][m]; per half: l2-normalize(GNT/rs), sigmoid,
// dot against P/Q columns from PQT; write ret / ret_a.
// ---------------------------------------------------------------------------
__global__ __launch_bounds__(256) void final_kernel(const float* __restrict__ GNT,
                                                    const float* __restrict__ PQT,
                                                    const float* __restrict__ bptr,
                                                    float* __restrict__ out_ret,
                                                    float* __restrict__ out_reta) {
  const int m = blockIdx.x * 256 + threadIdx.x;
  if (m >= 8000) return;
  const float b = bptr[0];
  const float inv_rs = 1.f / GNT[(size_t)128 * 8000 + m];
  float r1 = 0, r2 = 0, ra1 = 0, ra2 = 0;
#pragma unroll
  for (int h = 0; h < 2; ++h) {
    float ss = 0.f;
    for (int n = 0; n < 64; ++n) {
      const float t = GNT[(size_t)(h * 64 + n) * 8000 + m] * inv_rs;
      ss += t * t;
    }
    float nrm = fmaxf(sqrtf(ss), 1e-12f);
    const float inv = inv_rs / nrm;
    float s_p = 0.f, s_q = 0.f;
    for (int n = 0; n < 64; ++n) {
      const float t = GNT[(size_t)(h * 64 + n) * 8000 + m] * inv;
      const float g = 1.f / (1.f + expf(-t));
      s_p += PQT[(size_t)n * 8000 + m] * g;
      s_q += PQT[(size_t)(64 + n) * 8000 + m] * g;
    }
    if (h == 0) { r1 = s_p + b; r2 = s_q + b; }
    else        { ra1 = s_q + b; ra2 = s_p + b; }
  }
  out_ret[m * 2] = r1;  out_ret[m * 2 + 1] = r2;
  out_reta[m * 2] = ra1; out_reta[m * 2 + 1] = ra2;
}

// ---------------------------------------------------------------------------
extern "C" void kernel_launch(void* const* d_in, const int* in_sizes, int n_in,
                              void* d_out, int out_size, void* d_ws, size_t ws_size,
                              hipStream_t stream) {
  const float* feat   = (const float*)d_in[0];
  const float* feat_a = (const float*)d_in[1];
  const float* adj    = (const float*)d_in[2];
  const float* gneigh = (const float*)d_in[3];
  const float* w1     = (const float*)d_in[4];
  const float* w2     = (const float*)d_in[5];
  const float* dw     = (const float*)d_in[6];
  const float* db     = (const float*)d_in[7];

  float* out      = (float*)d_out;
  float* out_hid  = out;                 // [8000,64]
  float* out_h    = out + 512000;        // [8000,1024]
  float* out_ret  = out + 8704000;       // [8000,2]
  float* out_reta = out + 8720000;       // [8000,2]
  float* out_loss = out + 8736000;       // scalar

  char* ws = (char*)d_ws;
  float*  SfT  = (float*) (ws);              // [128][8000] f32 (atomic accum)
  float*  PQT  = (float*) (ws);              // alias: reused after fixup_S
  float*  Yf   = (float*) (ws + 4096000);    // [8000][64] f32 (atomic accum)
  float*  GNTf = (float*) (ws + 6144000);    // [144][8000] f32 (atomic accum)
  __bf16* R1T  = (__bf16*)(ws + 10752000);   // [128][8000] bf16
  __bf16* E    = (__bf16*)(ws + 10752000);   // alias: written after R1T dead
  __bf16* ET   = (__bf16*)(ws + 12800000);   // [144][8000] bf16
  __bf16* ZbT  = (__bf16*)(ws + 15104000);   // [64][8000] bf16
  __bf16* WdT  = (__bf16*)(ws + 16128000);   // [128][128]
  __bf16* W1bT = (__bf16*)(ws + 16160768);   // [64][1024]
  __bf16* W2bT = (__bf16*)(ws + 16291840);   // [1024][64]

  const int BIG = 1 << 30;

  // zero the three atomic accumulators (SfT, Yf, GNTf contiguous)
  hipMemsetAsync(ws, 0, 10752000, stream);
  prep_kernel<<<512, 256, 0, stream>>>(w1, w2, dw, W1bT, W2bT, WdT, ET, out_loss);

  // R1T = ([feat;feat_a] @ W1)^T   M=16000 K=1024 N=64, direct bf16
  gemm_tpl<16, 64, 1, 4, 0, 1, 1><<<1000, 256, 0, stream>>>(
      feat, feat_a, W1bT, R1T, 1024, 1024, 0, 1000, 1, 16, 8000);

  // SfT += (adj @ [fw1|fa1])^T     M=8000 K=8000 N=128, split-K=5
  gemm_tpl<32, 128, 2, 4, 0, 1, 4><<<1250, 512, 0, stream>>>(
      adj, adj, R1T, SfT, 8000, 8000, 0, 250, 1, 25, BIG);

  fixup_S<<<250, 256, 0, stream>>>(SfT, ET, ZbT, E, out_hid);

  // Yf += adj @ z                  M=8000 K=8000 N=64, split-K=5, row-major
  gemm_tpl<32, 64, 2, 4, 0, 0, 5><<<1250, 512, 0, stream>>>(
      adj, adj, ZbT, Yf, 8000, 8000, 64, 250, 1, 25, BIG);

  // h = Yf @ W2                    M=8000 K=64 N=1024, direct f32
  gemm_tpl<64, 128, 2, 2, 0, 0, 0><<<1000, 256, 0, stream>>>(
      Yf, Yf, W2bT, out_h, 64, 64, 1024, 125, 8, 1, BIG);

  // GNTf += (graph_neigh @ [emb|emb_a|1])^T  M=8000 K=8000 N=144, split-K=5
  gemm_tpl<32, 144, 2, 3, 0, 1, 4><<<1250, 384, 0, stream>>>(
      gneigh, gneigh, ET, GNTf, 8000, 8000, 0, 250, 1, 25, BIG);

  // PQT = (E @ blockdiag(disc_w))^T  M=8000 K=128 N=128, direct f32
  gemm_tpl<16, 128, 1, 4, 1, 1, 3><<<500, 256, 0, stream>>>(
      E, E, WdT, PQT, 128, 128, 0, 500, 1, 2, BIG);

  final_kernel<<<32, 256, 0, stream>>>(GNTf, PQT, db, out_ret, out_reta);
}